// Round 3
// baseline (2912.986 us; speedup 1.0000x reference)
//
#include <hip/hip_runtime.h>
#include <math.h>

#define TS 64
#define KT 16
#define LDP 68   // padded LDS leading dim: 16B-aligned rows, <=2-way bank conflicts (free)

// ---------------- GEMM: C = alpha*A@B (+ eye*I) (+ bias) (+ add), batched ----------------
__global__ __launch_bounds__(256)
void gemm_nn(const float* __restrict__ A, const float* __restrict__ B,
             float* __restrict__ C,
             int K, int lda, int ldb, int ldc,
             long sA, long sB, long sC,
             float alpha, float eye,
             const float* __restrict__ bias,
             const float* __restrict__ add, int ldadd)
{
  __shared__ float As[KT][LDP];
  __shared__ float Bs[KT][LDP];
  const int t = threadIdx.x;
  const int bz = blockIdx.z;
  const long rowBase = (long)blockIdx.y * TS;
  const long colBase = (long)blockIdx.x * TS;
  const float* Ab = A + bz * sA + rowBase * lda;
  const float* Bb = B + bz * sB + colBase;
  const int tx = t & 15, ty = t >> 4;
  const int ac = t & 15, ar = t >> 4;   // A tile: 64 rows x 16 cols
  const int bc = t & 63, br = t >> 6;   // B tile: 16 rows x 64 cols
  float acc[4][4] = {};
  for (int k0 = 0; k0 < K; k0 += KT) {
#pragma unroll
    for (int i = 0; i < 4; ++i)
      As[ac][ar + 16 * i] = Ab[(long)(ar + 16 * i) * lda + (k0 + ac)];
#pragma unroll
    for (int i = 0; i < 4; ++i)
      Bs[br + 4 * i][bc] = Bb[(long)(k0 + br + 4 * i) * ldb + bc];
    __syncthreads();
#pragma unroll
    for (int kk = 0; kk < KT; ++kk) {
      float a0[4], b0[4];
#pragma unroll
      for (int i = 0; i < 4; ++i) a0[i] = As[kk][ty * 4 + i];
#pragma unroll
      for (int j = 0; j < 4; ++j) b0[j] = Bs[kk][tx * 4 + j];
#pragma unroll
      for (int i = 0; i < 4; ++i)
#pragma unroll
        for (int j = 0; j < 4; ++j)
          acc[i][j] = fmaf(a0[i], b0[j], acc[i][j]);
    }
    __syncthreads();
  }
  float* Cb = C + bz * sC;
#pragma unroll
  for (int i = 0; i < 4; ++i) {
    long r = rowBase + ty * 4 + i;
#pragma unroll
    for (int j = 0; j < 4; ++j) {
      long c = colBase + tx * 4 + j;
      float v = alpha * acc[i][j];
      if (eye != 0.f && r == c) v += eye;
      if (bias) v += bias[c];
      if (add)  v += add[r * (long)ldadd + c];
      Cb[r * ldc + c] = v;
    }
  }
}

// ---------------- GEMM: C = alpha * A @ B^T  (B is (N,K) row-major), batched ----------------
__global__ __launch_bounds__(256)
void gemm_nt(const float* __restrict__ A, const float* __restrict__ B,
             float* __restrict__ C,
             int K, int lda, int ldb, int ldc,
             long sA, long sB, long sC, float alpha)
{
  __shared__ float As[KT][LDP];
  __shared__ float Bs[KT][LDP];
  const int t = threadIdx.x;
  const int bz = blockIdx.z;
  const long rowBase = (long)blockIdx.y * TS;
  const long colBase = (long)blockIdx.x * TS;
  const float* Ab = A + bz * sA + rowBase * lda;
  const float* Bb = B + bz * sB + colBase * ldb;
  const int tx = t & 15, ty = t >> 4;
  const int ac = t & 15, ar = t >> 4;
  float acc[4][4] = {};
  for (int k0 = 0; k0 < K; k0 += KT) {
#pragma unroll
    for (int i = 0; i < 4; ++i)
      As[ac][ar + 16 * i] = Ab[(long)(ar + 16 * i) * lda + (k0 + ac)];
#pragma unroll
    for (int i = 0; i < 4; ++i)
      Bs[ac][ar + 16 * i] = Bb[(long)(ar + 16 * i) * ldb + (k0 + ac)];
    __syncthreads();
#pragma unroll
    for (int kk = 0; kk < KT; ++kk) {
      float a0[4], b0[4];
#pragma unroll
      for (int i = 0; i < 4; ++i) a0[i] = As[kk][ty * 4 + i];
#pragma unroll
      for (int j = 0; j < 4; ++j) b0[j] = Bs[kk][tx * 4 + j];
#pragma unroll
      for (int i = 0; i < 4; ++i)
#pragma unroll
        for (int j = 0; j < 4; ++j)
          acc[i][j] = fmaf(a0[i], b0[j], acc[i][j]);
    }
    __syncthreads();
  }
  float* Cb = C + bz * sC;
#pragma unroll
  for (int i = 0; i < 4; ++i) {
    long r = rowBase + ty * 4 + i;
#pragma unroll
    for (int j = 0; j < 4; ++j) {
      long c = colBase + tx * 4 + j;
      Cb[r * ldc + c] = alpha * acc[i][j];
    }
  }
}

// ---------------- split-K GEMM NN with atomicAdd epilogue (C must be pre-zeroed) ----------------
__global__ __launch_bounds__(256)
void gemm_nn_splitk(const float* __restrict__ A, const float* __restrict__ B,
                    float* __restrict__ C,
                    int K, int ksplit, int lda, int ldb, int ldc,
                    long sA, long sB, long sC, float alpha)
{
  __shared__ float As[KT][LDP];
  __shared__ float Bs[KT][LDP];
  const int t = threadIdx.x;
  const int bz = blockIdx.z / ksplit;
  const int kc = blockIdx.z % ksplit;
  const int klen = K / ksplit;
  const int kbeg = kc * klen, kend = kbeg + klen;
  const long rowBase = (long)blockIdx.y * TS;
  const long colBase = (long)blockIdx.x * TS;
  const float* Ab = A + bz * sA + rowBase * lda;
  const float* Bb = B + bz * sB + colBase;
  const int tx = t & 15, ty = t >> 4;
  const int ac = t & 15, ar = t >> 4;
  const int bc = t & 63, br = t >> 6;
  float acc[4][4] = {};
  for (int k0 = kbeg; k0 < kend; k0 += KT) {
#pragma unroll
    for (int i = 0; i < 4; ++i)
      As[ac][ar + 16 * i] = Ab[(long)(ar + 16 * i) * lda + (k0 + ac)];
#pragma unroll
    for (int i = 0; i < 4; ++i)
      Bs[br + 4 * i][bc] = Bb[(long)(k0 + br + 4 * i) * ldb + bc];
    __syncthreads();
#pragma unroll
    for (int kk = 0; kk < KT; ++kk) {
      float a0[4], b0[4];
#pragma unroll
      for (int i = 0; i < 4; ++i) a0[i] = As[kk][ty * 4 + i];
#pragma unroll
      for (int j = 0; j < 4; ++j) b0[j] = Bs[kk][tx * 4 + j];
#pragma unroll
      for (int i = 0; i < 4; ++i)
#pragma unroll
        for (int j = 0; j < 4; ++j)
          acc[i][j] = fmaf(a0[i], b0[j], acc[i][j]);
    }
    __syncthreads();
  }
  float* Cb = C + bz * sC;
#pragma unroll
  for (int i = 0; i < 4; ++i) {
    long r = rowBase + ty * 4 + i;
#pragma unroll
    for (int j = 0; j < 4; ++j) {
      long c = colBase + tx * 4 + j;
      atomicAdd(&Cb[r * ldc + c], alpha * acc[i][j]);
    }
  }
}

// ---------------- LayerNorm over 512 cols, one block per row ----------------
__global__ __launch_bounds__(256)
void layernorm_k(const float* __restrict__ x, const float* __restrict__ g,
                 const float* __restrict__ b, float* __restrict__ y)
{
  const int row = blockIdx.x;
  const float* xr = x + (long)row * 512;
  float* yr = y + (long)row * 512;
  const int t = threadIdx.x;
  float2 v = ((const float2*)xr)[t];
  float s = v.x + v.y;
  float sq = v.x * v.x + v.y * v.y;
  for (int o = 32; o; o >>= 1) { s += __shfl_down(s, o, 64); sq += __shfl_down(sq, o, 64); }
  __shared__ float ss[4], sqq[4];
  __shared__ float mu_s, rs_s;
  const int lane = t & 63, w = t >> 6;
  if (!lane) { ss[w] = s; sqq[w] = sq; }
  __syncthreads();
  if (t == 0) {
    float S = ss[0] + ss[1] + ss[2] + ss[3];
    float SQ = sqq[0] + sqq[1] + sqq[2] + sqq[3];
    float mu = S * (1.f / 512.f);
    float var = SQ * (1.f / 512.f) - mu * mu;
    mu_s = mu; rs_s = rsqrtf(var + 1e-5f);
  }
  __syncthreads();
  const float mu = mu_s, rs = rs_s;
  float2 gv = ((const float2*)g)[t], bv = ((const float2*)b)[t];
  float2 o;
  o.x = (v.x - mu) * rs * gv.x + bv.x;
  o.y = (v.y - mu) * rs * gv.y + bv.y;
  ((float2*)yr)[t] = o;
}

// ---------------- row softmax (in place), one block per row ----------------
__global__ __launch_bounds__(256)
void softmax_rows(float* __restrict__ p, int cols)
{
  const long row = blockIdx.x;
  float* pr = p + row * (long)cols;
  const int t = threadIdx.x;
  __shared__ float red[4];
  const int lane = t & 63, w = t >> 6;
  float mx = -1e30f;
  for (int c = t; c < cols; c += 256) mx = fmaxf(mx, pr[c]);
  for (int o = 32; o; o >>= 1) mx = fmaxf(mx, __shfl_down(mx, o, 64));
  if (!lane) red[w] = mx;
  __syncthreads();
  const float bmx = fmaxf(fmaxf(red[0], red[1]), fmaxf(red[2], red[3]));
  __syncthreads();
  float s = 0.f;
  for (int c = t; c < cols; c += 256) { float e = __expf(pr[c] - bmx); pr[c] = e; s += e; }
  for (int o = 32; o; o >>= 1) s += __shfl_down(s, o, 64);
  if (!lane) red[w] = s;
  __syncthreads();
  const float inv = 1.f / (red[0] + red[1] + red[2] + red[3]);
  for (int c = t; c < cols; c += 256) pr[c] *= inv;
}

// ---------------- landmark means (contiguous 16-row chunks), unscaled ----------------
__global__ __launch_bounds__(256)
void landmarks_k(const float* __restrict__ qkv, float* __restrict__ ql, float* __restrict__ kl)
{
  const int idx = blockIdx.x * 256 + threadIdx.x;   // h*16384 + j*64 + d
  const int d = idx & 63;
  const int j = (idx >> 6) & 255;
  const int h = idx >> 14;
  const float* base = qkv + (long)(j * 16) * 1536 + h * 64 + d;
  float sq = 0.f, sk = 0.f;
#pragma unroll
  for (int r = 0; r < 16; ++r) { sq += base[r * 1536]; sk += base[r * 1536 + 512]; }
  ql[idx] = sq * (1.f / 16.f);
  kl[idx] = sk * (1.f / 16.f);
}

// ---------------- pinv helpers ----------------
__global__ void init_scal(float* s) { if (threadIdx.x < 2) s[threadIdx.x] = 0.f; }

__global__ __launch_bounds__(256)
void pinv_maxsums(const float* __restrict__ a2, float* __restrict__ scal)
{
  const int h = blockIdx.x, t = threadIdx.x;
  const float* m = a2 + (long)h * 65536;
  float rs = 0.f, cs = 0.f;
  for (int j = 0; j < 256; ++j) rs += m[t * 256 + j];   // row t sum  (|.| = . for softmax)
  for (int i = 0; i < 256; ++i) cs += m[i * 256 + t];   // col t sum
  for (int o = 32; o; o >>= 1) {
    rs = fmaxf(rs, __shfl_down(rs, o, 64));
    cs = fmaxf(cs, __shfl_down(cs, o, 64));
  }
  __shared__ float r4[4], c4[4];
  const int lane = t & 63, w = t >> 6;
  if (!lane) { r4[w] = rs; c4[w] = cs; }
  __syncthreads();
  if (t == 0) {
    float rm = fmaxf(fmaxf(r4[0], r4[1]), fmaxf(r4[2], r4[3]));
    float cm = fmaxf(fmaxf(c4[0], c4[1]), fmaxf(c4[2], c4[3]));
    atomicMax((int*)&scal[0], __float_as_int(rm));   // positive floats: int order == float order
    atomicMax((int*)&scal[1], __float_as_int(cm));
  }
}

__global__ __launch_bounds__(256)
void pinv_z0(const float* __restrict__ a2, const float* __restrict__ scal, float* __restrict__ z)
{
  const long idx = (long)blockIdx.x * 256 + threadIdx.x;  // h*65536 + i*256 + j
  const int j = idx & 255;
  const int i = (idx >> 8) & 255;
  const int h = idx >> 16;
  const float denom = scal[0] * scal[1];
  z[idx] = a2[(long)h * 65536 + j * 256 + i] / denom;
}

__global__ __launch_bounds__(256)
void eye_sub(const float* __restrict__ in, float* __restrict__ out, float c)
{
  const long idx = (long)blockIdx.x * 256 + threadIdx.x;
  const int j = idx & 255;
  const int i = (idx >> 8) & 255;
  out[idx] = (i == j ? c : 0.f) - in[idx];
}

__global__ void zero_k(float* p) { p[(long)blockIdx.x * 256 + threadIdx.x] = 0.f; }

// ---------------- depthwise conv-33 residual, added into out_conc ----------------
__global__ __launch_bounds__(256)
void conv_res_add(const float* __restrict__ qkv, const float* __restrict__ wres,
                  float* __restrict__ outc)
{
  const long idx = (long)blockIdx.x * 256 + threadIdx.x;  // i*512 + h*64 + d
  const int d = idx & 63;
  const int h = (idx >> 6) & 7;
  const long i = idx >> 9;
  const float* vcol = qkv + 1024 + h * 64 + d;
  float s = 0.f;
#pragma unroll
  for (int k2 = 0; k2 < 33; ++k2) {
    long src = i + k2 - 16;
    if (src >= 0 && src < 4096) s = fmaf(wres[h * 33 + k2], vcol[src * 1536], s);
  }
  outc[idx] += s;
}

// ---------------- host ----------------
extern "C" void kernel_launch(void* const* d_in, const int* in_sizes, int n_in,
                              void* d_out, int out_size, void* d_ws, size_t ws_size,
                              hipStream_t stream)
{
  const float* x     = (const float*)d_in[0];
  const float* ln_g  = (const float*)d_in[1];
  const float* ln_b  = (const float*)d_in[2];
  const float* w_qkv = (const float*)d_in[3];
  const float* w_out = (const float*)d_in[4];
  const float* b_out = (const float*)d_in[5];
  const float* w_res = (const float*)d_in[6];
  float* out = (float*)d_out;             // [0,2097152): x2 ; [2097152,...): attn
  float* ws  = (float*)d_ws;

  float* XLN  = ws;                       // 2,097,152
  float* QKV  = ws + 2097152;             // 6,291,456
  float* T1   = ws;                       // pass B alias of XLN+QKV (8,388,608 exactly)
  float* QL   = ws + 8388608;             // 131,072
  float* KL   = ws + 8519680;             // 131,072
  float* SIM3 = ws + 8650752;             // 8,388,608
  float* A2   = ws + 17039360;            // 524,288
  float* ZA   = ws + 17563648;
  float* ZB   = ws + 18087936;
  float* XZ   = ws + 18612224;
  float* TT   = ws + 19136512;
  float* TT2  = ws + 19660800;
  float* AV   = ws + 20185088;            // 131,072
  float* WW   = ws + 20316160;            // 131,072
  float* SCAL = ws + 20447232;            // 2
  float* OUTC = ws;                       // pass A alias of XLN (dead after qkv gemm)
  float* SIM1 = out + 2097152;            // scratch in (dead) attn region of d_out

  auto core = [&](const float* xin, bool needV) -> float* {
    layernorm_k<<<4096, 256, 0, stream>>>(xin, ln_g, ln_b, XLN);
    int ntiles = needV ? 24 : 16;  // skip v-projection in pass B
    gemm_nn<<<dim3(ntiles, 64, 1), 256, 0, stream>>>(XLN, w_qkv, QKV,
        512, 512, 1536, 1536, 0, 0, 0, 1.f, 0.f, nullptr, nullptr, 0);
    landmarks_k<<<512, 256, 0, stream>>>(QKV, QL, KL);
    // sim1 = s*q @ kl^T : (8, 4096, 256)
    gemm_nt<<<dim3(4, 64, 8), 256, 0, stream>>>(QKV, KL, SIM1,
        64, 1536, 64, 256, 64, 16384, 1048576, 0.125f);
    // sim2 = s*ql @ kl^T : (8, 256, 256)
    gemm_nt<<<dim3(4, 4, 8), 256, 0, stream>>>(QL, KL, A2,
        64, 64, 64, 256, 16384, 16384, 65536, 0.125f);
    // sim3 = s*ql @ k^T : (8, 256, 4096)
    gemm_nt<<<dim3(64, 4, 8), 256, 0, stream>>>(QL, QKV + 512, SIM3,
        64, 64, 1536, 4096, 16384, 64, 1048576, 0.125f);
    softmax_rows<<<32768, 256, 0, stream>>>(SIM1, 256);
    softmax_rows<<<2048, 256, 0, stream>>>(A2, 256);
    softmax_rows<<<2048, 256, 0, stream>>>(SIM3, 4096);
    // Moore-Penrose pinv of attn2 (global max over heads for the normalizer)
    init_scal<<<1, 64, 0, stream>>>(SCAL);
    pinv_maxsums<<<8, 256, 0, stream>>>(A2, SCAL);
    pinv_z0<<<2048, 256, 0, stream>>>(A2, SCAL, ZA);
    float* zc = ZA; float* zn = ZB;
    for (int it = 0; it < 6; ++it) {
      gemm_nn<<<dim3(4, 4, 8), 256, 0, stream>>>(A2, zc, XZ,
          256, 256, 256, 256, 65536, 65536, 65536, 1.f, 0.f, nullptr, nullptr, 0);
      eye_sub<<<2048, 256, 0, stream>>>(XZ, TT, 7.f);
      gemm_nn<<<dim3(4, 4, 8), 256, 0, stream>>>(XZ, TT, TT2,
          256, 256, 256, 256, 65536, 65536, 65536, -1.f, 15.f, nullptr, nullptr, 0);
      gemm_nn<<<dim3(4, 4, 8), 256, 0, stream>>>(XZ, TT2, TT,
          256, 256, 256, 256, 65536, 65536, 65536, -1.f, 13.f, nullptr, nullptr, 0);
      gemm_nn<<<dim3(4, 4, 8), 256, 0, stream>>>(zc, TT, zn,
          256, 256, 256, 256, 65536, 65536, 65536, 0.25f, 0.f, nullptr, nullptr, 0);
      float* tmp = zc; zc = zn; zn = tmp;
    }
    return zc;  // attn2_inv
  };

  // ---- Pass A: x2 = x + out1 ----
  float* zinv = core(x, true);
  // av = attn3 @ v : (8,256,64), split-K over 4096
  zero_k<<<512, 256, 0, stream>>>(AV);
  gemm_nn_splitk<<<dim3(1, 4, 64), 256, 0, stream>>>(SIM3, QKV + 1024, AV,
      4096, 8, 4096, 1536, 64, 1048576, 64, 16384, 1.f);
  // w = attn2_inv @ av : (8,256,64)
  gemm_nn<<<dim3(1, 4, 8), 256, 0, stream>>>(zinv, AV, WW,
      256, 256, 64, 64, 65536, 16384, 16384, 1.f, 0.f, nullptr, nullptr, 0);
  // out_conc = attn1 @ w, heads concatenated into (4096, 512)
  gemm_nn<<<dim3(1, 64, 8), 256, 0, stream>>>(SIM1, WW, OUTC,
      256, 256, 64, 512, 1048576, 16384, 64, 1.f, 0.f, nullptr, nullptr, 0);
  conv_res_add<<<8192, 256, 0, stream>>>(QKV, w_res, OUTC);
  // x2 = out_conc @ w_out + b_out + x  -> d_out[0:2097152]
  gemm_nn<<<dim3(8, 64, 1), 256, 0, stream>>>(OUTC, w_out, out,
      512, 512, 512, 512, 0, 0, 0, 1.f, 0.f, b_out, x, 512);

  // ---- Pass B: attn = (attn1 @ attn2_inv) @ attn3 ----
  zinv = core(out, false);
  gemm_nn<<<dim3(4, 64, 8), 256, 0, stream>>>(SIM1, zinv, T1,
      256, 256, 256, 256, 1048576, 65536, 1048576, 1.f, 0.f, nullptr, nullptr, 0);
  gemm_nn<<<dim3(64, 64, 8), 256, 0, stream>>>(T1, SIM3, out + 2097152,
      256, 256, 4096, 4096, 1048576, 1048576, 16777216, 1.f, 0.f, nullptr, nullptr, 0);
}

// Round 4
// 2165.713 us; speedup vs baseline: 1.3450x; 1.3450x over previous
//
#include <hip/hip_runtime.h>
#include <hip/hip_bf16.h>
#include <math.h>

#define TS 64
#define KT 16
#define LDP 68   // padded LDS leading dim for f32 GEMMs

typedef __attribute__((ext_vector_type(8))) short short8;
typedef __attribute__((ext_vector_type(4))) float f32x4;

// ---------------- GEMM: C = alpha*A@B (+ eye*I) (+ bias) (+ add), batched, f32 ----------------
__global__ __launch_bounds__(256)
void gemm_nn(const float* __restrict__ A, const float* __restrict__ B,
             float* __restrict__ C,
             int K, int lda, int ldb, int ldc,
             long sA, long sB, long sC,
             float alpha, float eye,
             const float* __restrict__ bias,
             const float* __restrict__ add, int ldadd)
{
  __shared__ float As[KT][LDP];
  __shared__ float Bs[KT][LDP];
  const int t = threadIdx.x;
  const int bz = blockIdx.z;
  const long rowBase = (long)blockIdx.y * TS;
  const long colBase = (long)blockIdx.x * TS;
  const float* Ab = A + bz * sA + rowBase * lda;
  const float* Bb = B + bz * sB + colBase;
  const int tx = t & 15, ty = t >> 4;
  const int ac = t & 15, ar = t >> 4;   // A tile: 64 rows x 16 cols
  const int bc = t & 63, br = t >> 6;   // B tile: 16 rows x 64 cols
  float acc[4][4] = {};
  for (int k0 = 0; k0 < K; k0 += KT) {
#pragma unroll
    for (int i = 0; i < 4; ++i)
      As[ac][ar + 16 * i] = Ab[(long)(ar + 16 * i) * lda + (k0 + ac)];
#pragma unroll
    for (int i = 0; i < 4; ++i)
      Bs[br + 4 * i][bc] = Bb[(long)(k0 + br + 4 * i) * ldb + bc];
    __syncthreads();
#pragma unroll
    for (int kk = 0; kk < KT; ++kk) {
      float a0[4], b0[4];
#pragma unroll
      for (int i = 0; i < 4; ++i) a0[i] = As[kk][ty * 4 + i];
#pragma unroll
      for (int j = 0; j < 4; ++j) b0[j] = Bs[kk][tx * 4 + j];
#pragma unroll
      for (int i = 0; i < 4; ++i)
#pragma unroll
        for (int j = 0; j < 4; ++j)
          acc[i][j] = fmaf(a0[i], b0[j], acc[i][j]);
    }
    __syncthreads();
  }
  float* Cb = C + bz * sC;
#pragma unroll
  for (int i = 0; i < 4; ++i) {
    long r = rowBase + ty * 4 + i;
#pragma unroll
    for (int j = 0; j < 4; ++j) {
      long c = colBase + tx * 4 + j;
      float v = alpha * acc[i][j];
      if (eye != 0.f && r == c) v += eye;
      if (bias) v += bias[c];
      if (add)  v += add[r * (long)ldadd + c];
      Cb[r * ldc + c] = v;
    }
  }
}

// ---------------- same f32 GEMM but bf16 output (f32 accumulate) ----------------
__global__ __launch_bounds__(256)
void gemm_nn_b16o(const float* __restrict__ A, const float* __restrict__ B,
                  __hip_bfloat16* __restrict__ C,
                  int K, int lda, int ldb, int ldc,
                  long sA, long sB, long sC)
{
  __shared__ float As[KT][LDP];
  __shared__ float Bs[KT][LDP];
  const int t = threadIdx.x;
  const int bz = blockIdx.z;
  const long rowBase = (long)blockIdx.y * TS;
  const long colBase = (long)blockIdx.x * TS;
  const float* Ab = A + bz * sA + rowBase * lda;
  const float* Bb = B + bz * sB + colBase;
  const int tx = t & 15, ty = t >> 4;
  const int ac = t & 15, ar = t >> 4;
  const int bc = t & 63, br = t >> 6;
  float acc[4][4] = {};
  for (int k0 = 0; k0 < K; k0 += KT) {
#pragma unroll
    for (int i = 0; i < 4; ++i)
      As[ac][ar + 16 * i] = Ab[(long)(ar + 16 * i) * lda + (k0 + ac)];
#pragma unroll
    for (int i = 0; i < 4; ++i)
      Bs[br + 4 * i][bc] = Bb[(long)(k0 + br + 4 * i) * ldb + bc];
    __syncthreads();
#pragma unroll
    for (int kk = 0; kk < KT; ++kk) {
      float a0[4], b0[4];
#pragma unroll
      for (int i = 0; i < 4; ++i) a0[i] = As[kk][ty * 4 + i];
#pragma unroll
      for (int j = 0; j < 4; ++j) b0[j] = Bs[kk][tx * 4 + j];
#pragma unroll
      for (int i = 0; i < 4; ++i)
#pragma unroll
        for (int j = 0; j < 4; ++j)
          acc[i][j] = fmaf(a0[i], b0[j], acc[i][j]);
    }
    __syncthreads();
  }
  __hip_bfloat16* Cb = C + bz * sC;
#pragma unroll
  for (int i = 0; i < 4; ++i) {
    long r = rowBase + ty * 4 + i;
#pragma unroll
    for (int j = 0; j < 4; ++j) {
      long c = colBase + tx * 4 + j;
      Cb[r * ldc + c] = __float2bfloat16(acc[i][j]);
    }
  }
}

// ---------------- GEMM: C = alpha * A @ B^T  (B is (N,K) row-major), batched, f32 ----------------
__global__ __launch_bounds__(256)
void gemm_nt(const float* __restrict__ A, const float* __restrict__ B,
             float* __restrict__ C,
             int K, int lda, int ldb, int ldc,
             long sA, long sB, long sC, float alpha)
{
  __shared__ float As[KT][LDP];
  __shared__ float Bs[KT][LDP];
  const int t = threadIdx.x;
  const int bz = blockIdx.z;
  const long rowBase = (long)blockIdx.y * TS;
  const long colBase = (long)blockIdx.x * TS;
  const float* Ab = A + bz * sA + rowBase * lda;
  const float* Bb = B + bz * sB + colBase * ldb;
  const int tx = t & 15, ty = t >> 4;
  const int ac = t & 15, ar = t >> 4;
  float acc[4][4] = {};
  for (int k0 = 0; k0 < K; k0 += KT) {
#pragma unroll
    for (int i = 0; i < 4; ++i)
      As[ac][ar + 16 * i] = Ab[(long)(ar + 16 * i) * lda + (k0 + ac)];
#pragma unroll
    for (int i = 0; i < 4; ++i)
      Bs[ac][ar + 16 * i] = Bb[(long)(ar + 16 * i) * ldb + (k0 + ac)];
    __syncthreads();
#pragma unroll
    for (int kk = 0; kk < KT; ++kk) {
      float a0[4], b0[4];
#pragma unroll
      for (int i = 0; i < 4; ++i) a0[i] = As[kk][ty * 4 + i];
#pragma unroll
      for (int j = 0; j < 4; ++j) b0[j] = Bs[kk][tx * 4 + j];
#pragma unroll
      for (int i = 0; i < 4; ++i)
#pragma unroll
        for (int j = 0; j < 4; ++j)
          acc[i][j] = fmaf(a0[i], b0[j], acc[i][j]);
    }
    __syncthreads();
  }
  float* Cb = C + bz * sC;
#pragma unroll
  for (int i = 0; i < 4; ++i) {
    long r = rowBase + ty * 4 + i;
#pragma unroll
    for (int j = 0; j < 4; ++j) {
      long c = colBase + tx * 4 + j;
      Cb[r * ldc + c] = alpha * acc[i][j];
    }
  }
}

// ---------------- split-K GEMM NN with atomicAdd epilogue (C must be pre-zeroed) ----------------
__global__ __launch_bounds__(256)
void gemm_nn_splitk(const float* __restrict__ A, const float* __restrict__ B,
                    float* __restrict__ C,
                    int K, int ksplit, int lda, int ldb, int ldc,
                    long sA, long sB, long sC, float alpha)
{
  __shared__ float As[KT][LDP];
  __shared__ float Bs[KT][LDP];
  const int t = threadIdx.x;
  const int bz = blockIdx.z / ksplit;
  const int kc = blockIdx.z % ksplit;
  const int klen = K / ksplit;
  const int kbeg = kc * klen, kend = kbeg + klen;
  const long rowBase = (long)blockIdx.y * TS;
  const long colBase = (long)blockIdx.x * TS;
  const float* Ab = A + bz * sA + rowBase * lda;
  const float* Bb = B + bz * sB + colBase;
  const int tx = t & 15, ty = t >> 4;
  const int ac = t & 15, ar = t >> 4;
  const int bc = t & 63, br = t >> 6;
  float acc[4][4] = {};
  for (int k0 = kbeg; k0 < kend; k0 += KT) {
#pragma unroll
    for (int i = 0; i < 4; ++i)
      As[ac][ar + 16 * i] = Ab[(long)(ar + 16 * i) * lda + (k0 + ac)];
#pragma unroll
    for (int i = 0; i < 4; ++i)
      Bs[br + 4 * i][bc] = Bb[(long)(k0 + br + 4 * i) * ldb + bc];
    __syncthreads();
#pragma unroll
    for (int kk = 0; kk < KT; ++kk) {
      float a0[4], b0[4];
#pragma unroll
      for (int i = 0; i < 4; ++i) a0[i] = As[kk][ty * 4 + i];
#pragma unroll
      for (int j = 0; j < 4; ++j) b0[j] = Bs[kk][tx * 4 + j];
#pragma unroll
      for (int i = 0; i < 4; ++i)
#pragma unroll
        for (int j = 0; j < 4; ++j)
          acc[i][j] = fmaf(a0[i], b0[j], acc[i][j]);
    }
    __syncthreads();
  }
  float* Cb = C + bz * sC;
#pragma unroll
  for (int i = 0; i < 4; ++i) {
    long r = rowBase + ty * 4 + i;
#pragma unroll
    for (int j = 0; j < 4; ++j) {
      long c = colBase + tx * 4 + j;
      atomicAdd(&Cb[r * ldc + c], alpha * acc[i][j]);
    }
  }
}

// ---------------- MFMA bf16 NT GEMM: C(f32, MxN) = A(bf16, MxK) @ B(bf16, NxK)^T ----------------
// 128x128 tile, BK=32, 256 thr = 4 waves (2x2), each wave 64x64 = 4x4 frags of 16x16x32.
// LDS rows padded to 40 elems (80 B = 20-bank stride -> 2-way conflicts, free per m136).
__global__ __launch_bounds__(256)
void mfma_nt_bf16(const __hip_bfloat16* __restrict__ A,
                  const __hip_bfloat16* __restrict__ B,
                  float* __restrict__ C, int K)
{
  __shared__ short As[128 * 40];
  __shared__ short Bs[128 * 40];
  const int h = blockIdx.z;
  const long rowBase = (long)blockIdx.y * 128;
  const long colBase = (long)blockIdx.x * 128;
  const short* Ag = (const short*)A + (long)h * 1048576 + rowBase * 256;
  const short* Bg = (const short*)B + (long)h * 1048576 + colBase * 256;
  const int t = threadIdx.x;
  const int wave = t >> 6, lane = t & 63;
  const int wm = wave >> 1, wn = wave & 1;
  const int l15 = lane & 15, l4 = lane >> 4;
  f32x4 acc[4][4] = {};
  for (int k0 = 0; k0 < K; k0 += 32) {
    __syncthreads();
#pragma unroll
    for (int i = 0; i < 4; ++i) {
      int flat = t + 256 * i;          // 0..1023
      int row = flat >> 2, seg = flat & 3;
      *(short8*)(&As[row * 40 + seg * 8]) = *(const short8*)(Ag + (long)row * 256 + k0 + seg * 8);
      *(short8*)(&Bs[row * 40 + seg * 8]) = *(const short8*)(Bg + (long)row * 256 + k0 + seg * 8);
    }
    __syncthreads();
    short8 a[4], b[4];
#pragma unroll
    for (int m = 0; m < 4; ++m)
      a[m] = *(const short8*)(&As[(wm * 64 + m * 16 + l15) * 40 + l4 * 8]);
#pragma unroll
    for (int n = 0; n < 4; ++n)
      b[n] = *(const short8*)(&Bs[(wn * 64 + n * 16 + l15) * 40 + l4 * 8]);
#pragma unroll
    for (int m = 0; m < 4; ++m)
#pragma unroll
      for (int n = 0; n < 4; ++n)
        acc[m][n] = __builtin_amdgcn_mfma_f32_16x16x32_bf16(a[m], b[n], acc[m][n], 0, 0, 0);
  }
  float* Cb = C + (long)h * 16777216;
#pragma unroll
  for (int m = 0; m < 4; ++m) {
#pragma unroll
    for (int n = 0; n < 4; ++n) {
      long col = colBase + wn * 64 + n * 16 + l15;
      long rbase = rowBase + wm * 64 + m * 16 + l4 * 4;
#pragma unroll
      for (int r = 0; r < 4; ++r)
        Cb[(rbase + r) * 4096 + col] = acc[m][n][r];
    }
  }
}

// ---------------- transpose+convert: (8,256,4096) f32 -> (8,4096,256) bf16 ----------------
__global__ __launch_bounds__(256)
void transpose_bf16(const float* __restrict__ in, __hip_bfloat16* __restrict__ outp)
{
  __shared__ float tile[64][65];
  const int h = blockIdx.z;
  const int k0 = blockIdx.y * 64;   // source row (k)
  const int n0 = blockIdx.x * 64;   // source col (n)
  const float* src = in + (long)h * 1048576;
  __hip_bfloat16* dst = outp + (long)h * 1048576;
  const int t = threadIdx.x;
#pragma unroll
  for (int i = 0; i < 16; ++i) {
    int idx = t + 256 * i;
    int r = idx >> 6, c = idx & 63;
    tile[r][c] = src[(long)(k0 + r) * 4096 + n0 + c];
  }
  __syncthreads();
#pragma unroll
  for (int i = 0; i < 16; ++i) {
    int idx = t + 256 * i;
    int r = idx >> 6, c = idx & 63;
    dst[(long)(n0 + r) * 256 + k0 + c] = __float2bfloat16(tile[c][r]);
  }
}

// ---------------- LayerNorm over 512 cols, one block per row ----------------
__global__ __launch_bounds__(256)
void layernorm_k(const float* __restrict__ x, const float* __restrict__ g,
                 const float* __restrict__ b, float* __restrict__ y)
{
  const int row = blockIdx.x;
  const float* xr = x + (long)row * 512;
  float* yr = y + (long)row * 512;
  const int t = threadIdx.x;
  float2 v = ((const float2*)xr)[t];
  float s = v.x + v.y;
  float sq = v.x * v.x + v.y * v.y;
  for (int o = 32; o; o >>= 1) { s += __shfl_down(s, o, 64); sq += __shfl_down(sq, o, 64); }
  __shared__ float ss[4], sqq[4];
  __shared__ float mu_s, rs_s;
  const int lane = t & 63, w = t >> 6;
  if (!lane) { ss[w] = s; sqq[w] = sq; }
  __syncthreads();
  if (t == 0) {
    float S = ss[0] + ss[1] + ss[2] + ss[3];
    float SQ = sqq[0] + sqq[1] + sqq[2] + sqq[3];
    float mu = S * (1.f / 512.f);
    float var = SQ * (1.f / 512.f) - mu * mu;
    mu_s = mu; rs_s = rsqrtf(var + 1e-5f);
  }
  __syncthreads();
  const float mu = mu_s, rs = rs_s;
  float2 gv = ((const float2*)g)[t], bv = ((const float2*)b)[t];
  float2 o;
  o.x = (v.x - mu) * rs * gv.x + bv.x;
  o.y = (v.y - mu) * rs * gv.y + bv.y;
  ((float2*)yr)[t] = o;
}

// ---------------- row softmax (in place), one block per row ----------------
__global__ __launch_bounds__(256)
void softmax_rows(float* __restrict__ p, int cols)
{
  const long row = blockIdx.x;
  float* pr = p + row * (long)cols;
  const int t = threadIdx.x;
  __shared__ float red[4];
  const int lane = t & 63, w = t >> 6;
  float mx = -1e30f;
  for (int c = t; c < cols; c += 256) mx = fmaxf(mx, pr[c]);
  for (int o = 32; o; o >>= 1) mx = fmaxf(mx, __shfl_down(mx, o, 64));
  if (!lane) red[w] = mx;
  __syncthreads();
  const float bmx = fmaxf(fmaxf(red[0], red[1]), fmaxf(red[2], red[3]));
  __syncthreads();
  float s = 0.f;
  for (int c = t; c < cols; c += 256) { float e = __expf(pr[c] - bmx); pr[c] = e; s += e; }
  for (int o = 32; o; o >>= 1) s += __shfl_down(s, o, 64);
  if (!lane) red[w] = s;
  __syncthreads();
  const float inv = 1.f / (red[0] + red[1] + red[2] + red[3]);
  for (int c = t; c < cols; c += 256) pr[c] *= inv;
}

// ---------------- landmark means (contiguous 16-row chunks), unscaled ----------------
__global__ __launch_bounds__(256)
void landmarks_k(const float* __restrict__ qkv, float* __restrict__ ql, float* __restrict__ kl)
{
  const int idx = blockIdx.x * 256 + threadIdx.x;   // h*16384 + j*64 + d
  const int d = idx & 63;
  const int j = (idx >> 6) & 255;
  const int h = idx >> 14;
  const float* base = qkv + (long)(j * 16) * 1536 + h * 64 + d;
  float sq = 0.f, sk = 0.f;
#pragma unroll
  for (int r = 0; r < 16; ++r) { sq += base[r * 1536]; sk += base[r * 1536 + 512]; }
  ql[idx] = sq * (1.f / 16.f);
  kl[idx] = sk * (1.f / 16.f);
}

// ---------------- pinv helpers ----------------
__global__ void init_scal(float* s) { if (threadIdx.x < 2) s[threadIdx.x] = 0.f; }

__global__ __launch_bounds__(256)
void pinv_maxsums(const float* __restrict__ a2, float* __restrict__ scal)
{
  const int h = blockIdx.x, t = threadIdx.x;
  const float* m = a2 + (long)h * 65536;
  float rs = 0.f, cs = 0.f;
  for (int j = 0; j < 256; ++j) rs += m[t * 256 + j];
  for (int i = 0; i < 256; ++i) cs += m[i * 256 + t];
  for (int o = 32; o; o >>= 1) {
    rs = fmaxf(rs, __shfl_down(rs, o, 64));
    cs = fmaxf(cs, __shfl_down(cs, o, 64));
  }
  __shared__ float r4[4], c4[4];
  const int lane = t & 63, w = t >> 6;
  if (!lane) { r4[w] = rs; c4[w] = cs; }
  __syncthreads();
  if (t == 0) {
    float rm = fmaxf(fmaxf(r4[0], r4[1]), fmaxf(r4[2], r4[3]));
    float cm = fmaxf(fmaxf(c4[0], c4[1]), fmaxf(c4[2], c4[3]));
    atomicMax((int*)&scal[0], __float_as_int(rm));
    atomicMax((int*)&scal[1], __float_as_int(cm));
  }
}

__global__ __launch_bounds__(256)
void pinv_z0(const float* __restrict__ a2, const float* __restrict__ scal, float* __restrict__ z)
{
  const long idx = (long)blockIdx.x * 256 + threadIdx.x;
  const int j = idx & 255;
  const int i = (idx >> 8) & 255;
  const int h = idx >> 16;
  const float denom = scal[0] * scal[1];
  z[idx] = a2[(long)h * 65536 + j * 256 + i] / denom;
}

__global__ __launch_bounds__(256)
void eye_sub(const float* __restrict__ in, float* __restrict__ out, float c)
{
  const long idx = (long)blockIdx.x * 256 + threadIdx.x;
  const int j = idx & 255;
  const int i = (idx >> 8) & 255;
  out[idx] = (i == j ? c : 0.f) - in[idx];
}

__global__ void zero_k(float* p) { p[(long)blockIdx.x * 256 + threadIdx.x] = 0.f; }

// ---------------- depthwise conv-33 residual, added into out_conc ----------------
__global__ __launch_bounds__(256)
void conv_res_add(const float* __restrict__ qkv, const float* __restrict__ wres,
                  float* __restrict__ outc)
{
  const long idx = (long)blockIdx.x * 256 + threadIdx.x;  // i*512 + h*64 + d
  const int d = idx & 63;
  const int h = (idx >> 6) & 7;
  const long i = idx >> 9;
  const float* vcol = qkv + 1024 + h * 64 + d;
  float s = 0.f;
#pragma unroll
  for (int k2 = 0; k2 < 33; ++k2) {
    long src = i + k2 - 16;
    if (src >= 0 && src < 4096) s = fmaf(wres[h * 33 + k2], vcol[src * 1536], s);
  }
  outc[idx] += s;
}

// ---------------- host ----------------
extern "C" void kernel_launch(void* const* d_in, const int* in_sizes, int n_in,
                              void* d_out, int out_size, void* d_ws, size_t ws_size,
                              hipStream_t stream)
{
  const float* x     = (const float*)d_in[0];
  const float* ln_g  = (const float*)d_in[1];
  const float* ln_b  = (const float*)d_in[2];
  const float* w_qkv = (const float*)d_in[3];
  const float* w_out = (const float*)d_in[4];
  const float* b_out = (const float*)d_in[5];
  const float* w_res = (const float*)d_in[6];
  float* out = (float*)d_out;             // [0,2097152): x2 ; [2097152,...): attn
  float* ws  = (float*)d_ws;

  float* XLN  = ws;                       // 2,097,152
  float* QKV  = ws + 2097152;             // 6,291,456
  float* QL   = ws + 8388608;             // 131,072
  float* KL   = ws + 8519680;             // 131,072
  float* SIM3 = ws + 8650752;             // 8,388,608
  float* A2   = ws + 17039360;            // 524,288
  float* ZA   = ws + 17563648;
  float* ZB   = ws + 18087936;
  float* XZ   = ws + 18612224;
  float* TT   = ws + 19136512;
  float* TT2  = ws + 19660800;
  float* AV   = ws + 20185088;            // 131,072
  float* WW   = ws + 20316160;            // 131,072
  float* SCAL = ws + 20447232;            // 2
  float* OUTC = ws;                       // pass A alias of XLN (dead after qkv gemm)
  float* SIM1 = out + 2097152;            // scratch in (dead) attn region of d_out
  // pass-B bf16 buffers, aliasing the dead XLN+QKV region (each 16.8 MB):
  __hip_bfloat16* T1B = (__hip_bfloat16*)ws;                   // (8,4096,256) bf16
  __hip_bfloat16* S3T = (__hip_bfloat16*)(ws + 4194304);       // (8,4096,256) bf16 (SIM3^T)

  auto core = [&](const float* xin, bool needV) -> float* {
    layernorm_k<<<4096, 256, 0, stream>>>(xin, ln_g, ln_b, XLN);
    int ntiles = needV ? 24 : 16;  // skip v-projection in pass B
    gemm_nn<<<dim3(ntiles, 64, 1), 256, 0, stream>>>(XLN, w_qkv, QKV,
        512, 512, 1536, 1536, 0, 0, 0, 1.f, 0.f, nullptr, nullptr, 0);
    landmarks_k<<<512, 256, 0, stream>>>(QKV, QL, KL);
    // sim1 = s*q @ kl^T : (8, 4096, 256)
    gemm_nt<<<dim3(4, 64, 8), 256, 0, stream>>>(QKV, KL, SIM1,
        64, 1536, 64, 256, 64, 16384, 1048576, 0.125f);
    // sim2 = s*ql @ kl^T : (8, 256, 256)
    gemm_nt<<<dim3(4, 4, 8), 256, 0, stream>>>(QL, KL, A2,
        64, 64, 64, 256, 16384, 16384, 65536, 0.125f);
    // sim3 = s*ql @ k^T : (8, 256, 4096)
    gemm_nt<<<dim3(64, 4, 8), 256, 0, stream>>>(QL, QKV + 512, SIM3,
        64, 64, 1536, 4096, 16384, 64, 1048576, 0.125f);
    softmax_rows<<<32768, 256, 0, stream>>>(SIM1, 256);
    softmax_rows<<<2048, 256, 0, stream>>>(A2, 256);
    softmax_rows<<<2048, 256, 0, stream>>>(SIM3, 4096);
    // Moore-Penrose pinv of attn2 (global max over heads for the normalizer)
    init_scal<<<1, 64, 0, stream>>>(SCAL);
    pinv_maxsums<<<8, 256, 0, stream>>>(A2, SCAL);
    pinv_z0<<<2048, 256, 0, stream>>>(A2, SCAL, ZA);
    float* zc = ZA; float* zn = ZB;
    for (int it = 0; it < 6; ++it) {
      gemm_nn<<<dim3(4, 4, 8), 256, 0, stream>>>(A2, zc, XZ,
          256, 256, 256, 256, 65536, 65536, 65536, 1.f, 0.f, nullptr, nullptr, 0);
      eye_sub<<<2048, 256, 0, stream>>>(XZ, TT, 7.f);
      gemm_nn<<<dim3(4, 4, 8), 256, 0, stream>>>(XZ, TT, TT2,
          256, 256, 256, 256, 65536, 65536, 65536, -1.f, 15.f, nullptr, nullptr, 0);
      gemm_nn<<<dim3(4, 4, 8), 256, 0, stream>>>(XZ, TT2, TT,
          256, 256, 256, 256, 65536, 65536, 65536, -1.f, 13.f, nullptr, nullptr, 0);
      gemm_nn<<<dim3(4, 4, 8), 256, 0, stream>>>(zc, TT, zn,
          256, 256, 256, 256, 65536, 65536, 65536, 0.25f, 0.f, nullptr, nullptr, 0);
      float* tmp = zc; zc = zn; zn = tmp;
    }
    return zc;  // attn2_inv
  };

  // ---- Pass A: x2 = x + out1 ----
  float* zinv = core(x, true);
  // av = attn3 @ v : (8,256,64), split-K over 4096
  zero_k<<<512, 256, 0, stream>>>(AV);
  gemm_nn_splitk<<<dim3(1, 4, 64), 256, 0, stream>>>(SIM3, QKV + 1024, AV,
      4096, 8, 4096, 1536, 64, 1048576, 64, 16384, 1.f);
  // w = attn2_inv @ av : (8,256,64)
  gemm_nn<<<dim3(1, 4, 8), 256, 0, stream>>>(zinv, AV, WW,
      256, 256, 64, 64, 65536, 16384, 16384, 1.f, 0.f, nullptr, nullptr, 0);
  // out_conc = attn1 @ w, heads concatenated into (4096, 512)
  gemm_nn<<<dim3(1, 64, 8), 256, 0, stream>>>(SIM1, WW, OUTC,
      256, 256, 64, 512, 1048576, 16384, 64, 1.f, 0.f, nullptr, nullptr, 0);
  conv_res_add<<<8192, 256, 0, stream>>>(QKV, w_res, OUTC);
  // x2 = out_conc @ w_out + b_out + x  -> d_out[0:2097152]
  gemm_nn<<<dim3(8, 64, 1), 256, 0, stream>>>(OUTC, w_out, out,
      512, 512, 512, 512, 0, 0, 0, 1.f, 0.f, b_out, x, 512);

  // ---- Pass B: attn = (attn1 @ attn2_inv) @ attn3, big GEMM on matrix cores ----
  zinv = core(out, false);
  // T1 (bf16) = attn1 @ attn2_inv : (8,4096,256), f32 accumulate, bf16 store into dead XLN region
  gemm_nn_b16o<<<dim3(4, 64, 8), 256, 0, stream>>>(SIM1, zinv, T1B,
      256, 256, 256, 256, 1048576, 65536, 1048576);
  // S3T (bf16) = SIM3^T per head : (8,4096,256), into dead QKV region
  transpose_bf16<<<dim3(64, 4, 8), 256, 0, stream>>>(SIM3, S3T);
  // attn = T1B @ S3T^T : (8,4096,4096) f32, bf16 MFMA
  mfma_nt_bf16<<<dim3(32, 32, 8), 256, 0, stream>>>(T1B, S3T, out + 2097152, 256);
}